// Round 1
// baseline (676.984 us; speedup 1.0000x reference)
//
#include <hip/hip_runtime.h>
#include <hip/hip_bf16.h>
#include <cmath>

#define NB 64
#define SS 512
#define DD 1536
#define DH 6144
#define NHID 1024

// ws layout in floats
#define WS_E 0                       // [128][1536]  rows 0..63 = entity1, 64..127 = entity2
#define WS_Q (128 * 1536)            // [128][1536]  q1 rows 0..63, q2 rows 64..127
#define WS_FEAT (2 * 128 * 1536)     // [64][6144]   [sa2 | sa1 | cls | e2]
#define WS_PART (WS_FEAT + 64 * 6144)// [64][8][1544] acc[1536], m, l, pad
#define PSTR 1544

__device__ __forceinline__ float dot4(float4 a, float4 b) {
  return a.x * b.x + a.y * b.y + a.z * b.z + a.w * b.w;
}

// ---------------------------------------------------------------- entity ----
__global__ __launch_bounds__(256) void k_entity(const float* __restrict__ x,
                                                const int* __restrict__ locs,
                                                const float* __restrict__ b2,
                                                float* __restrict__ ws,
                                                float* __restrict__ out) {
  const int b = blockIdx.x;
  const int t = threadIdx.x;
  const int l0 = locs[b * 4 + 0], l1 = locs[b * 4 + 1];
  const int l2 = locs[b * 4 + 2], l3 = locs[b * 4 + 3];
  const float* xb = x + (size_t)b * SS * DD;
  const float inv1 = 1.0f / (float)(l1 - l0 - 1);
  const float inv2 = 1.0f / (float)(l3 - l2 - 1);
#pragma unroll
  for (int j = 0; j < 6; ++j) {
    const int d = t + 256 * j;
    float s1 = 0.f, s2 = 0.f;
    for (int s = l0 + 1; s < l1; ++s) s1 += xb[(size_t)s * DD + d];
    for (int s = l2 + 1; s < l3; ++s) s2 += xb[(size_t)s * DD + d];
    const float e1 = s1 * inv1, e2 = s2 * inv2;
    ws[WS_E + (size_t)b * DD + d] = e1;
    ws[WS_E + (size_t)(NB + b) * DD + d] = e2;
    ws[WS_FEAT + (size_t)b * DH + 3072 + d] = xb[d];  // cls (s = 0)
    ws[WS_FEAT + (size_t)b * DH + 4608 + d] = e2;
  }
  if (t == 0) out[b] = b2[0];
}

// ---------------------------------------------------------------- q gemv ----
// q[v][n] = dot(E[v], W_in[n]); 16v x 64n block tile, wave = 16v x 16n, lane 2x2
__global__ __launch_bounds__(256) void k_qgemv(const float* __restrict__ Wm,
                                               float* __restrict__ ws) {
  const int bx = blockIdx.x;
  const int vt = bx & 7, nt = bx >> 3;  // same-nt blocks adjacent -> W rows L2-shared
  const int t = threadIdx.x;
  const int w = t >> 6, lane = t & 63;
  const int vi = lane >> 3, ni = lane & 7;
  const int v0 = vt * 16 + vi * 2;
  const int n0 = nt * 64 + w * 16 + ni * 2;
  const float4* e0p = (const float4*)(ws + WS_E + (size_t)v0 * DD);
  const float4* e1p = (const float4*)(ws + WS_E + (size_t)(v0 + 1) * DD);
  const float4* w0p = (const float4*)(Wm + (size_t)n0 * DD);
  const float4* w1p = (const float4*)(Wm + (size_t)(n0 + 1) * DD);
  float a00 = 0, a01 = 0, a10 = 0, a11 = 0;
#pragma unroll 2
  for (int k = 0; k < DD / 4; ++k) {
    const float4 ea = e0p[k], eb = e1p[k];
    const float4 wa = w0p[k], wb = w1p[k];
    a00 += dot4(ea, wa); a01 += dot4(ea, wb);
    a10 += dot4(eb, wa); a11 += dot4(eb, wb);
  }
  float* q = ws + WS_Q;
  q[(size_t)v0 * DD + n0] = a00;
  q[(size_t)v0 * DD + n0 + 1] = a01;
  q[(size_t)(v0 + 1) * DD + n0] = a10;
  q[(size_t)(v0 + 1) * DD + n0 + 1] = a11;
}

// ----------------------------------------------------------------- flash ----
// One block per (batch, 64-pos chunk). Chunks 0..3 -> pool1 (imp1), 4..7 -> pool2.
// Each wave: online softmax over its 16 positions, acc fragment in registers.
__global__ __launch_bounds__(256) void k_flash(const float* __restrict__ x,
                                               const int* __restrict__ locs,
                                               const int* __restrict__ seps,
                                               float* __restrict__ ws) {
  const int bc = blockIdx.x;
  const int b = bc >> 3, c = bc & 7;
  const int pool = c >> 2;
  const int t = threadIdx.x, w = t >> 6, lane = t & 63;
  const int l0 = locs[b * 4 + 0], l1 = locs[b * 4 + 1];
  const int l2 = locs[b * 4 + 2], l3 = locs[b * 4 + 3];
  const int sep0 = seps[b * 2 + 0], sep1 = seps[b * 2 + 1];
  const float* xb = x + (size_t)b * SS * DD;
  const float4* qv = (const float4*)(ws + WS_Q + (size_t)(pool * NB + b) * DD);
  float4 qf[6], acc[6];
#pragma unroll
  for (int j = 0; j < 6; ++j) {
    qf[j] = qv[lane + 64 * j];
    acc[j] = make_float4(0.f, 0.f, 0.f, 0.f);
  }
  float m = -INFINITY, l = 0.f;
  const int sbase = c * 64;

  for (int i = 0; i < 16; i += 2) {
    const int s0 = sbase + w + 4 * i;
    const int s1 = s0 + 4;
    const bool va = pool ? ((s0 >= sep1 && s0 <= l2) || s0 >= l3)
                         : (s0 <= l0 || (s0 >= l1 && s0 < sep0));
    const bool vb = pool ? ((s1 >= sep1 && s1 <= l2) || s1 >= l3)
                         : (s1 <= l0 || (s1 >= l1 && s1 < sep0));
    float4 xa[6], xc[6];
    float pa = 0.f, pb = 0.f;
    if (va) {
      const float4* xs = (const float4*)(xb + (size_t)s0 * DD);
#pragma unroll
      for (int j = 0; j < 6; ++j) xa[j] = xs[lane + 64 * j];
    }
    if (vb) {
      const float4* xs = (const float4*)(xb + (size_t)s1 * DD);
#pragma unroll
      for (int j = 0; j < 6; ++j) xc[j] = xs[lane + 64 * j];
    }
    if (va) {
      const float d0 = dot4(xa[0], qf[0]) + dot4(xa[1], qf[1]);
      const float d1 = dot4(xa[2], qf[2]) + dot4(xa[3], qf[3]);
      const float d2 = dot4(xa[4], qf[4]) + dot4(xa[5], qf[5]);
      pa = d0 + d1 + d2;
    }
    if (vb) {
      const float d0 = dot4(xc[0], qf[0]) + dot4(xc[1], qf[1]);
      const float d1 = dot4(xc[2], qf[2]) + dot4(xc[3], qf[3]);
      const float d2 = dot4(xc[4], qf[4]) + dot4(xc[5], qf[5]);
      pb = d0 + d1 + d2;
    }
#pragma unroll
    for (int o = 1; o < 64; o <<= 1) {
      pa += __shfl_xor(pa, o, 64);
      pb += __shfl_xor(pb, o, 64);
    }
    if (va) {
      if (pa <= m) {
        const float e = __expf(pa - m);
        l += e;
#pragma unroll
        for (int j = 0; j < 6; ++j) {
          acc[j].x += e * xa[j].x; acc[j].y += e * xa[j].y;
          acc[j].z += e * xa[j].z; acc[j].w += e * xa[j].w;
        }
      } else {
        const float r = __expf(m - pa);
        m = pa; l = l * r + 1.f;
#pragma unroll
        for (int j = 0; j < 6; ++j) {
          acc[j].x = acc[j].x * r + xa[j].x; acc[j].y = acc[j].y * r + xa[j].y;
          acc[j].z = acc[j].z * r + xa[j].z; acc[j].w = acc[j].w * r + xa[j].w;
        }
      }
    }
    if (vb) {
      if (pb <= m) {
        const float e = __expf(pb - m);
        l += e;
#pragma unroll
        for (int j = 0; j < 6; ++j) {
          acc[j].x += e * xc[j].x; acc[j].y += e * xc[j].y;
          acc[j].z += e * xc[j].z; acc[j].w += e * xc[j].w;
        }
      } else {
        const float r = __expf(m - pb);
        m = pb; l = l * r + 1.f;
#pragma unroll
        for (int j = 0; j < 6; ++j) {
          acc[j].x = acc[j].x * r + xc[j].x; acc[j].y = acc[j].y * r + xc[j].y;
          acc[j].z = acc[j].z * r + xc[j].z; acc[j].w = acc[j].w * r + xc[j].w;
        }
      }
    }
  }

  // -------- combine 4 waves via LDS, write chunk partial --------
  __shared__ float lm[4], ll[4];
  __shared__ float accs[4][DD];
  if (lane == 0) { lm[w] = m; ll[w] = l; }
  __syncthreads();
  const float m0 = fmaxf(fmaxf(lm[0], lm[1]), fmaxf(lm[2], lm[3]));
  const float sc = (m > -INFINITY) ? __expf(m - m0) : 0.f;
#pragma unroll
  for (int j = 0; j < 6; ++j) {
    float4 a = acc[j];
    a.x *= sc; a.y *= sc; a.z *= sc; a.w *= sc;
    *(float4*)&accs[w][4 * (lane + 64 * j)] = a;
  }
  __syncthreads();
  float* part = ws + WS_PART + (size_t)(b * 8 + c) * PSTR;
#pragma unroll
  for (int jj = 0; jj < 6; ++jj) {
    const int col = t + 256 * jj;
    part[col] = accs[0][col] + accs[1][col] + accs[2][col] + accs[3][col];
  }
  if (t == 0) {
    float ls = 0.f;
#pragma unroll
    for (int ww = 0; ww < 4; ++ww)
      ls += ll[ww] * ((lm[ww] > -INFINITY) ? __expf(lm[ww] - m0) : 0.f);
    part[1536] = m0;
    part[1537] = ls;
  }
}

// --------------------------------------------------------------- combine ----
__global__ __launch_bounds__(256) void k_comb(float* __restrict__ ws) {
  const int bx = blockIdx.x;
  const int b = bx >> 1, pool = bx & 1;
  const int t = threadIdx.x;
  const float* base = ws + WS_PART + (size_t)(b * 8 + pool * 4) * PSTR;
  const float m0 = base[0 * PSTR + 1536], m1 = base[1 * PSTR + 1536];
  const float m2 = base[2 * PSTR + 1536], m3 = base[3 * PSTR + 1536];
  const float mm = fmaxf(fmaxf(m0, m1), fmaxf(m2, m3));
  const float s0 = __expf(m0 - mm), s1 = __expf(m1 - mm);
  const float s2 = __expf(m2 - mm), s3 = __expf(m3 - mm);
  const float lsum = base[0 * PSTR + 1537] * s0 + base[1 * PSTR + 1537] * s1 +
                     base[2 * PSTR + 1537] * s2 + base[3 * PSTR + 1537] * s3;
  const float inv = 1.f / lsum;
  const int off = pool ? 0 : 1536;  // pool2 -> sent_attn2 at 0, pool1 -> 1536
  float* feat = ws + WS_FEAT + (size_t)b * DH + off;
#pragma unroll
  for (int jj = 0; jj < 6; ++jj) {
    const int col = t + 256 * jj;
    const float v = base[0 * PSTR + col] * s0 + base[1 * PSTR + col] * s1 +
                    base[2 * PSTR + col] * s2 + base[3 * PSTR + col] * s3;
    feat[col] = v * inv;
  }
}

// ------------------------------------------------------------------- MLP ----
// h[b][n] = leaky(feat[b] . W1[n] + b1[n]); out[b] += h * W2[n]  (atomic)
// wave = 8b x 8n, lane (bi, ni); block = 4 waves stacked in n (8b x 32n)
__global__ __launch_bounds__(256) void k_mlp(const float* __restrict__ W1,
                                             const float* __restrict__ b1,
                                             const float* __restrict__ alpha,
                                             const float* __restrict__ W2,
                                             const float* __restrict__ ws,
                                             float* __restrict__ out) {
  const int bx = blockIdx.x;
  const int bt = bx & 7, nt = bx >> 3;  // bt 0..7, nt 0..31
  const int t = threadIdx.x, w = t >> 6, lane = t & 63;
  const int bi = lane >> 3, ni = lane & 7;
  const int bb = bt * 8 + bi;
  const int n = nt * 32 + w * 8 + ni;
  const float4* f = (const float4*)(ws + WS_FEAT + (size_t)bb * DH);
  const float4* wr = (const float4*)(W1 + (size_t)n * DH);
  float a0 = 0, a1 = 0, a2 = 0, a3 = 0;
  for (int k = 0; k < DH / 4; k += 4) {
    a0 += dot4(f[k + 0], wr[k + 0]);
    a1 += dot4(f[k + 1], wr[k + 1]);
    a2 += dot4(f[k + 2], wr[k + 2]);
    a3 += dot4(f[k + 3], wr[k + 3]);
  }
  float h = (a0 + a1) + (a2 + a3) + b1[n];
  const float al = alpha[0];
  h = (h >= 0.f) ? h : al * h;
  float val = h * W2[n];
  val += __shfl_xor(val, 1, 64);
  val += __shfl_xor(val, 2, 64);
  val += __shfl_xor(val, 4, 64);
  if (ni == 0) atomicAdd(&out[bb], val);
}

// ------------------------------------------------------------------ launch --
extern "C" void kernel_launch(void* const* d_in, const int* in_sizes, int n_in,
                              void* d_out, int out_size, void* d_ws, size_t ws_size,
                              hipStream_t stream) {
  const float* x     = (const float*)d_in[0];
  const float* Wm    = (const float*)d_in[1];
  const float* W1    = (const float*)d_in[2];
  const float* b1    = (const float*)d_in[3];
  const float* alpha = (const float*)d_in[4];
  const float* W2    = (const float*)d_in[5];
  const float* b2    = (const float*)d_in[6];
  const int* locs    = (const int*)d_in[7];
  const int* seps    = (const int*)d_in[8];
  float* out = (float*)d_out;
  float* ws = (float*)d_ws;

  hipLaunchKernelGGL(k_entity, dim3(NB), dim3(256), 0, stream, x, locs, b2, ws, out);
  hipLaunchKernelGGL(k_qgemv, dim3(192), dim3(256), 0, stream, Wm, ws);
  hipLaunchKernelGGL(k_flash, dim3(NB * 8), dim3(256), 0, stream, x, locs, seps, ws);
  hipLaunchKernelGGL(k_comb, dim3(NB * 2), dim3(256), 0, stream, ws);
  hipLaunchKernelGGL(k_mlp, dim3(256), dim3(256), 0, stream, W1, b1, alpha, W2, ws, out);
}

// Round 2
// 486.791 us; speedup vs baseline: 1.3907x; 1.3907x over previous
//
#include <hip/hip_runtime.h>
#include <hip/hip_bf16.h>
#include <cmath>

#define NB 64
#define SS 512
#define DD 1536
#define DH 6144

// ws layout (floats)
#define WS_E     0                 // [128][1536]: rows 0..63 e1, 64..127 e2
#define WS_Q     196608            // 2 k-split slots of [128][1536]
#define WS_FEAT  589824            // [64][6144]  [sa2 | sa1 | cls | e2]
#define WS_PART  983040            // [64][32][1544] flash chunk partials
#define WS_HPART 4145152           // [4][1024][64] mlp split-K partials
#define PSTR 1544

__device__ __forceinline__ float dot4(float4 a, float4 b) {
  return a.x * b.x + a.y * b.y + a.z * b.z + a.w * b.w;
}

// ---------------------------------------------------------------- entity ----
// grid (6, 64): block handles 256 d-cols of one batch
__global__ __launch_bounds__(256) void k_entity(const float* __restrict__ x,
                                                const int* __restrict__ locs,
                                                float* __restrict__ ws) {
  const int seg = blockIdx.x;
  const int b = blockIdx.y;
  const int d = seg * 256 + threadIdx.x;
  const int l0 = locs[b * 4 + 0], l1 = locs[b * 4 + 1];
  const int l2 = locs[b * 4 + 2], l3 = locs[b * 4 + 3];
  const float* xb = x + (size_t)b * SS * DD;
  float s1 = 0.f, s2 = 0.f;
  for (int s = l0 + 1; s < l1; ++s) s1 += xb[(size_t)s * DD + d];
  for (int s = l2 + 1; s < l3; ++s) s2 += xb[(size_t)s * DD + d];
  const float e1 = s1 / (float)(l1 - l0 - 1);
  const float e2 = s2 / (float)(l3 - l2 - 1);
  ws[WS_E + (size_t)b * DD + d] = e1;
  ws[WS_E + (size_t)(NB + b) * DD + d] = e2;
  ws[WS_FEAT + (size_t)b * DH + 3072 + d] = xb[d];  // cls (s=0)
  ws[WS_FEAT + (size_t)b * DH + 4608 + d] = e2;
}

// ---------------------------------------------------------------- q gemv ----
// q[v][n] = dot(E[v], W_in[n]); grid 384 = 8 vt x 24 nt x 2 ksplit
__global__ __launch_bounds__(256) void k_qgemv(const float* __restrict__ Wm,
                                               float* __restrict__ ws) {
  const int bx = blockIdx.x;
  const int ks = bx / 192, r = bx % 192;
  const int vt = r & 7, nt = r >> 3;
  const int t = threadIdx.x, w = t >> 6, lane = t & 63;
  const int vi = lane >> 3, ni = lane & 7;
  const int v0 = vt * 16 + vi * 2;
  const int n0 = nt * 64 + w * 16 + ni * 2;
  const float4* e0p = (const float4*)(ws + WS_E + (size_t)v0 * DD) + ks * 192;
  const float4* e1p = (const float4*)(ws + WS_E + (size_t)(v0 + 1) * DD) + ks * 192;
  const float4* w0p = (const float4*)(Wm + (size_t)n0 * DD) + ks * 192;
  const float4* w1p = (const float4*)(Wm + (size_t)(n0 + 1) * DD) + ks * 192;
  float a00 = 0, a01 = 0, a10 = 0, a11 = 0;
#pragma unroll 2
  for (int k = 0; k < 192; ++k) {
    const float4 ea = e0p[k], eb = e1p[k];
    const float4 wa = w0p[k], wb = w1p[k];
    a00 += dot4(ea, wa); a01 += dot4(ea, wb);
    a10 += dot4(eb, wa); a11 += dot4(eb, wb);
  }
  float* q = ws + WS_Q + (size_t)ks * 196608;
  q[(size_t)v0 * DD + n0] = a00;
  q[(size_t)v0 * DD + n0 + 1] = a01;
  q[(size_t)(v0 + 1) * DD + n0] = a10;
  q[(size_t)(v0 + 1) * DD + n0 + 1] = a11;
}

// ----------------------------------------------------------------- flash ----
// one WAVE per (batch, 16-pos chunk); chunks 0..15 -> pool1, 16..31 -> pool2
__global__ __launch_bounds__(64, 4) void k_flash(const float* __restrict__ x,
                                                 const int* __restrict__ locs,
                                                 const int* __restrict__ seps,
                                                 float* __restrict__ ws) {
  const int bc = blockIdx.x;
  const int b = bc >> 5, c = bc & 31;
  const int pool = c >> 4;
  const int lane = threadIdx.x;
  const int l0 = locs[b * 4 + 0], l1 = locs[b * 4 + 1];
  const int l2 = locs[b * 4 + 2], l3 = locs[b * 4 + 3];
  const int sep0 = seps[b * 2 + 0], sep1 = seps[b * 2 + 1];
  const float* xb = x + (size_t)b * SS * DD;
  const float* q0 = ws + WS_Q + (size_t)(pool * NB + b) * DD;
  const float* q1 = q0 + 196608;
  float4 qf[6], acc[6];
#pragma unroll
  for (int j = 0; j < 6; ++j) {
    const float4 a = ((const float4*)q0)[lane + 64 * j];
    const float4 bq = ((const float4*)q1)[lane + 64 * j];
    qf[j] = make_float4(a.x + bq.x, a.y + bq.y, a.z + bq.z, a.w + bq.w);
    acc[j] = make_float4(0.f, 0.f, 0.f, 0.f);
  }
  float m = -INFINITY, l = 0.f;
  const int sbase = pool * 256 + (c & 15) * 16;
#pragma unroll 2
  for (int i = 0; i < 16; ++i) {
    const int s = sbase + i;
    const bool v = pool ? ((s >= sep1 && s <= l2) || s >= l3)
                        : (s <= l0 || (s >= l1 && s < sep0));
    if (!v) continue;
    const float4* xs = (const float4*)(xb + (size_t)s * DD);
    float4 xf[6];
#pragma unroll
    for (int j = 0; j < 6; ++j) xf[j] = xs[lane + 64 * j];
    float p = dot4(xf[0], qf[0]) + dot4(xf[1], qf[1]) + dot4(xf[2], qf[2]) +
              dot4(xf[3], qf[3]) + dot4(xf[4], qf[4]) + dot4(xf[5], qf[5]);
#pragma unroll
    for (int o = 1; o < 64; o <<= 1) p += __shfl_xor(p, o, 64);
    if (p <= m) {
      const float e = __expf(p - m);
      l += e;
#pragma unroll
      for (int j = 0; j < 6; ++j) {
        acc[j].x += e * xf[j].x; acc[j].y += e * xf[j].y;
        acc[j].z += e * xf[j].z; acc[j].w += e * xf[j].w;
      }
    } else {
      const float r = __expf(m - p);
      m = p; l = l * r + 1.f;
#pragma unroll
      for (int j = 0; j < 6; ++j) {
        acc[j].x = acc[j].x * r + xf[j].x; acc[j].y = acc[j].y * r + xf[j].y;
        acc[j].z = acc[j].z * r + xf[j].z; acc[j].w = acc[j].w * r + xf[j].w;
      }
    }
  }
  float* part = ws + WS_PART + (size_t)(b * 32 + c) * PSTR;
#pragma unroll
  for (int j = 0; j < 6; ++j) *(float4*)&part[4 * (lane + 64 * j)] = acc[j];
  if (lane == 0) { part[1536] = m; part[1537] = l; }
}

// --------------------------------------------------------------- combine ----
// grid 128 = (b, pool); merge 16 chunk partials -> feat
__global__ __launch_bounds__(256) void k_comb(float* __restrict__ ws) {
  const int bx = blockIdx.x;
  const int b = bx >> 1, pool = bx & 1;
  const int t = threadIdx.x;
  const float* base = ws + WS_PART + (size_t)(b * 32 + pool * 16) * PSTR;
  float ms[16];
  float mm = -INFINITY;
#pragma unroll
  for (int cc = 0; cc < 16; ++cc) {
    ms[cc] = base[cc * PSTR + 1536];
    mm = fmaxf(mm, ms[cc]);
  }
  float sc[16];
  float lsum = 0.f;
#pragma unroll
  for (int cc = 0; cc < 16; ++cc) {
    sc[cc] = __expf(ms[cc] - mm);
    lsum += base[cc * PSTR + 1537] * sc[cc];
  }
  const float inv = 1.f / lsum;
  const int off = pool ? 0 : 1536;  // pool1 -> sa1 @1536, pool2 -> sa2 @0
  float* feat = ws + WS_FEAT + (size_t)b * DH + off;
#pragma unroll
  for (int jj = 0; jj < 6; ++jj) {
    const int col = t + 256 * jj;
    float v = 0.f;
#pragma unroll
    for (int cc = 0; cc < 16; ++cc) v += base[cc * PSTR + col] * sc[cc];
    feat[col] = v * inv;
  }
}

// ------------------------------------------------------------------- MLP ----
// h[b][n] partials: grid 256 = 64 n-tiles x 4 k-splits. Block: 16 n-rows.
// Lane split: ln = lane>>4 (n-row within wave), lk = lane&15 (k-slice).
// feat K-chunk (64 x 256 f32 = 64 KB) staged in LDS; W1 read coalesced once.
__global__ __launch_bounds__(256) void k_mlp(const float* __restrict__ W1,
                                             float* __restrict__ ws) {
  __shared__ float lds[16384];
  const int bx = blockIdx.x;
  const int nt = bx & 63, ks = bx >> 6;
  const int t = threadIdx.x, w = t >> 6, lane = t & 63;
  const int ln = lane >> 4, lk = lane & 15;
  const int n = nt * 16 + w * 4 + ln;
  const int kb0 = ks * 1536;
  float acc[64];
#pragma unroll
  for (int b = 0; b < 64; ++b) acc[b] = 0.f;
  const float* feat = ws + WS_FEAT;
  for (int step = 0; step < 6; ++step) {
    const int kb = kb0 + step * 256;
    __syncthreads();  // previous step's readers done before overwrite
#pragma unroll
    for (int jj = 0; jj < 16; ++jj) {
      const int f = t + 256 * jj;          // float4 id 0..4095
      const int row = f >> 6, c4 = f & 63;
      *(float4*)&lds[row * 256 + 4 * c4] =
          *(const float4*)&feat[(size_t)row * DH + kb + 4 * c4];
    }
    __syncthreads();
    const float* wr = W1 + (size_t)n * DH + kb + 4 * lk;
    const float4 w0 = *(const float4*)(wr);
    const float4 w1 = *(const float4*)(wr + 64);
    const float4 w2 = *(const float4*)(wr + 128);
    const float4 w3 = *(const float4*)(wr + 192);
#pragma unroll
    for (int b = 0; b < 64; ++b) {
      const float* lb = &lds[b * 256 + 4 * lk];
      const float4 f0 = *(const float4*)(lb);
      const float4 f1 = *(const float4*)(lb + 64);
      const float4 f2 = *(const float4*)(lb + 128);
      const float4 f3 = *(const float4*)(lb + 192);
      acc[b] += dot4(f0, w0) + dot4(f1, w1) + dot4(f2, w2) + dot4(f3, w3);
    }
  }
  // reduce acc over the 16 k-lanes via XOR-swizzled LDS transpose
  __syncthreads();
#pragma unroll
  for (int i = 0; i < 16; ++i) {
    *(float4*)&lds[t * 64 + 4 * ((i ^ lk) & 15)] =
        make_float4(acc[4 * i], acc[4 * i + 1], acc[4 * i + 2], acc[4 * i + 3]);
  }
  __syncthreads();
  float4 h = make_float4(0.f, 0.f, 0.f, 0.f);
#pragma unroll
  for (int kp = 0; kp < 16; ++kp) {
    const float4 v =
        *(const float4*)&lds[(w * 64 + ln * 16 + kp) * 64 + 4 * ((lk ^ kp) & 15)];
    h.x += v.x; h.y += v.y; h.z += v.z; h.w += v.w;
  }
  *(float4*)&ws[WS_HPART + ((size_t)ks * 1024 + n) * 64 + 4 * lk] = h;
}

// ------------------------------------------------------------------- out ----
// block per batch: sum split-K, bias, leaky, dot W2, block-reduce
__global__ __launch_bounds__(256) void k_out(const float* __restrict__ b1,
                                             const float* __restrict__ alpha,
                                             const float* __restrict__ W2,
                                             const float* __restrict__ b2,
                                             const float* __restrict__ ws,
                                             float* __restrict__ out) {
  const int b = blockIdx.x;
  const int t = threadIdx.x;
  const float al = alpha[0];
  float partial = 0.f;
#pragma unroll
  for (int u = 0; u < 4; ++u) {
    const int n = t + 256 * u;
    float hs = 0.f;
#pragma unroll
    for (int ksp = 0; ksp < 4; ++ksp)
      hs += ws[WS_HPART + ((size_t)ksp * 1024 + n) * 64 + b];
    float h = hs + b1[n];
    h = (h >= 0.f) ? h : al * h;
    partial += h * W2[n];
  }
#pragma unroll
  for (int o = 1; o < 64; o <<= 1) partial += __shfl_xor(partial, o, 64);
  __shared__ float wsum[4];
  if ((t & 63) == 0) wsum[t >> 6] = partial;
  __syncthreads();
  if (t == 0) out[b] = b2[0] + wsum[0] + wsum[1] + wsum[2] + wsum[3];
}

// ------------------------------------------------------------------ launch --
extern "C" void kernel_launch(void* const* d_in, const int* in_sizes, int n_in,
                              void* d_out, int out_size, void* d_ws, size_t ws_size,
                              hipStream_t stream) {
  const float* x     = (const float*)d_in[0];
  const float* Wm    = (const float*)d_in[1];
  const float* W1    = (const float*)d_in[2];
  const float* b1    = (const float*)d_in[3];
  const float* alpha = (const float*)d_in[4];
  const float* W2    = (const float*)d_in[5];
  const float* b2    = (const float*)d_in[6];
  const int* locs    = (const int*)d_in[7];
  const int* seps    = (const int*)d_in[8];
  float* out = (float*)d_out;
  float* ws = (float*)d_ws;

  hipLaunchKernelGGL(k_entity, dim3(6, 64), dim3(256), 0, stream, x, locs, ws);
  hipLaunchKernelGGL(k_qgemv, dim3(384), dim3(256), 0, stream, Wm, ws);
  hipLaunchKernelGGL(k_flash, dim3(NB * 32), dim3(64), 0, stream, x, locs, seps, ws);
  hipLaunchKernelGGL(k_comb, dim3(NB * 2), dim3(256), 0, stream, ws);
  hipLaunchKernelGGL(k_mlp, dim3(256), dim3(256), 0, stream, W1, ws);
  hipLaunchKernelGGL(k_out, dim3(NB), dim3(256), 0, stream, b1, alpha, W2, b2, ws, out);
}

// Round 3
// 448.657 us; speedup vs baseline: 1.5089x; 1.0850x over previous
//
#include <hip/hip_runtime.h>
#include <hip/hip_bf16.h>
#include <cmath>

#define NB 64
#define SS 512
#define DD 1536
#define DH 6144

// ws layout (floats)
#define WS_E     0                 // [128][1536]: rows 0..63 e1, 64..127 e2
#define WS_Q     196608            // 2 k-split slots of [128][1536]
#define WS_FEAT  589824            // [64][6144]  [sa2 | sa1 | cls | e2]
#define WS_PART  983040            // [64][32][1544] flash chunk partials
#define WS_HPART 4145152           // [8][64][1024] mlp split-K partials
#define PSTR 1544

__device__ __forceinline__ float dot4(float4 a, float4 b) {
  return a.x * b.x + a.y * b.y + a.z * b.z + a.w * b.w;
}

// ---------------------------------------------------------------- entity ----
__global__ __launch_bounds__(256) void k_entity(const float* __restrict__ x,
                                                const int* __restrict__ locs,
                                                float* __restrict__ ws) {
  const int seg = blockIdx.x;
  const int b = blockIdx.y;
  const int d = seg * 256 + threadIdx.x;
  const int l0 = locs[b * 4 + 0], l1 = locs[b * 4 + 1];
  const int l2 = locs[b * 4 + 2], l3 = locs[b * 4 + 3];
  const float* xb = x + (size_t)b * SS * DD;
  float s1 = 0.f, s2 = 0.f;
  for (int s = l0 + 1; s < l1; ++s) s1 += xb[(size_t)s * DD + d];
  for (int s = l2 + 1; s < l3; ++s) s2 += xb[(size_t)s * DD + d];
  const float e1 = s1 / (float)(l1 - l0 - 1);
  const float e2 = s2 / (float)(l3 - l2 - 1);
  ws[WS_E + (size_t)b * DD + d] = e1;
  ws[WS_E + (size_t)(NB + b) * DD + d] = e2;
  ws[WS_FEAT + (size_t)b * DH + 3072 + d] = xb[d];  // cls (s=0)
  ws[WS_FEAT + (size_t)b * DH + 4608 + d] = e2;
}

// ---------------------------------------------------------------- q gemv ----
__global__ __launch_bounds__(256) void k_qgemv(const float* __restrict__ Wm,
                                               float* __restrict__ ws) {
  const int bx = blockIdx.x;
  const int ks = bx / 192, r = bx % 192;
  const int vt = r & 7, nt = r >> 3;
  const int t = threadIdx.x, w = t >> 6, lane = t & 63;
  const int vi = lane >> 3, ni = lane & 7;
  const int v0 = vt * 16 + vi * 2;
  const int n0 = nt * 64 + w * 16 + ni * 2;
  const float4* e0p = (const float4*)(ws + WS_E + (size_t)v0 * DD) + ks * 192;
  const float4* e1p = (const float4*)(ws + WS_E + (size_t)(v0 + 1) * DD) + ks * 192;
  const float4* w0p = (const float4*)(Wm + (size_t)n0 * DD) + ks * 192;
  const float4* w1p = (const float4*)(Wm + (size_t)(n0 + 1) * DD) + ks * 192;
  float a00 = 0, a01 = 0, a10 = 0, a11 = 0;
#pragma unroll 2
  for (int k = 0; k < 192; ++k) {
    const float4 ea = e0p[k], eb = e1p[k];
    const float4 wa = w0p[k], wb = w1p[k];
    a00 += dot4(ea, wa); a01 += dot4(ea, wb);
    a10 += dot4(eb, wa); a11 += dot4(eb, wb);
  }
  float* q = ws + WS_Q + (size_t)ks * 196608;
  q[(size_t)v0 * DD + n0] = a00;
  q[(size_t)v0 * DD + n0 + 1] = a01;
  q[(size_t)(v0 + 1) * DD + n0] = a10;
  q[(size_t)(v0 + 1) * DD + n0 + 1] = a11;
}

// ----------------------------------------------------------------- flash ----
// one WAVE per (batch, 16-pos chunk); branchless pairwise online softmax
__global__ __launch_bounds__(64, 2) void k_flash(const float* __restrict__ x,
                                                 const int* __restrict__ locs,
                                                 const int* __restrict__ seps,
                                                 float* __restrict__ ws) {
  const int bc = blockIdx.x;
  const int b = bc >> 5, c = bc & 31;
  const int pool = c >> 4;
  const int lane = threadIdx.x;
  const int l0 = locs[b * 4 + 0], l1 = locs[b * 4 + 1];
  const int l2 = locs[b * 4 + 2], l3 = locs[b * 4 + 3];
  const int sep0 = seps[b * 2 + 0], sep1 = seps[b * 2 + 1];
  const float* xb = x + (size_t)b * SS * DD;
  const float* q0 = ws + WS_Q + (size_t)(pool * NB + b) * DD;
  const float* q1 = q0 + 196608;
  float4 qf[6], acc[6];
#pragma unroll
  for (int j = 0; j < 6; ++j) {
    const float4 a = ((const float4*)q0)[lane + 64 * j];
    const float4 bq = ((const float4*)q1)[lane + 64 * j];
    qf[j] = make_float4(a.x + bq.x, a.y + bq.y, a.z + bq.z, a.w + bq.w);
    acc[j] = make_float4(0.f, 0.f, 0.f, 0.f);
  }
  float m = -1e30f, l = 0.f;
  const int sbase = pool * 256 + (c & 15) * 16;
#pragma unroll 2
  for (int i = 0; i < 16; i += 2) {
    const int s0 = sbase + i;
    const int s1 = s0 + 1;
    const bool va = pool ? ((s0 >= sep1 && s0 <= l2) || s0 >= l3)
                         : (s0 <= l0 || (s0 >= l1 && s0 < sep0));
    const bool vb = pool ? ((s1 >= sep1 && s1 <= l2) || s1 >= l3)
                         : (s1 <= l0 || (s1 >= l1 && s1 < sep0));
    const float4* xsa = (const float4*)(xb + (size_t)s0 * DD);
    const float4* xsb = (const float4*)(xb + (size_t)s1 * DD);
    float4 xa[6], xc[6];
#pragma unroll
    for (int j = 0; j < 6; ++j) { xa[j] = xsa[lane + 64 * j]; xc[j] = xsb[lane + 64 * j]; }
    float pa = dot4(xa[0], qf[0]) + dot4(xa[1], qf[1]) + dot4(xa[2], qf[2]) +
               dot4(xa[3], qf[3]) + dot4(xa[4], qf[4]) + dot4(xa[5], qf[5]);
    float pb = dot4(xc[0], qf[0]) + dot4(xc[1], qf[1]) + dot4(xc[2], qf[2]) +
               dot4(xc[3], qf[3]) + dot4(xc[4], qf[4]) + dot4(xc[5], qf[5]);
#pragma unroll
    for (int o = 1; o < 64; o <<= 1) {
      pa += __shfl_xor(pa, o, 64);
      pb += __shfl_xor(pb, o, 64);
    }
    pa = va ? pa : -INFINITY;
    pb = vb ? pb : -INFINITY;
    const float mn = fmaxf(m, fmaxf(pa, pb));
    const float r = __expf(m - mn);
    const float ea = __expf(pa - mn);
    const float eb = __expf(pb - mn);
    m = mn;
    l = l * r + ea + eb;
#pragma unroll
    for (int j = 0; j < 6; ++j) {
      acc[j].x = acc[j].x * r + ea * xa[j].x + eb * xc[j].x;
      acc[j].y = acc[j].y * r + ea * xa[j].y + eb * xc[j].y;
      acc[j].z = acc[j].z * r + ea * xa[j].z + eb * xc[j].z;
      acc[j].w = acc[j].w * r + ea * xa[j].w + eb * xc[j].w;
    }
  }
  float* part = ws + WS_PART + (size_t)(b * 32 + c) * PSTR;
#pragma unroll
  for (int j = 0; j < 6; ++j) *(float4*)&part[4 * (lane + 64 * j)] = acc[j];
  if (lane == 0) { part[1536] = m; part[1537] = l; }
}

// --------------------------------------------------------------- combine ----
__global__ __launch_bounds__(256) void k_comb(float* __restrict__ ws) {
  const int bx = blockIdx.x;
  const int b = bx >> 1, pool = bx & 1;
  const int t = threadIdx.x;
  const float* base = ws + WS_PART + (size_t)(b * 32 + pool * 16) * PSTR;
  float ms[16];
  float mm = -1e30f;
#pragma unroll
  for (int cc = 0; cc < 16; ++cc) {
    ms[cc] = base[cc * PSTR + 1536];
    mm = fmaxf(mm, ms[cc]);
  }
  float sc[16];
  float lsum = 0.f;
#pragma unroll
  for (int cc = 0; cc < 16; ++cc) {
    sc[cc] = __expf(ms[cc] - mm);
    lsum += base[cc * PSTR + 1537] * sc[cc];
  }
  const float inv = 1.f / lsum;
  const int off = pool ? 0 : 1536;
  float* feat = ws + WS_FEAT + (size_t)b * DH + off;
#pragma unroll
  for (int jj = 0; jj < 6; ++jj) {
    const int col = t + 256 * jj;
    float v = 0.f;
#pragma unroll
    for (int cc = 0; cc < 16; ++cc) v += base[cc * PSTR + col] * sc[cc];
    feat[col] = v * inv;
  }
}

// ------------------------------------------------------------------- MLP ----
// grid 512 = 4 bt (16 batches) x 16 nt (64 n) x 8 ks (768 k). Block 256 thr.
// Lane: lk = lane&15 (k-slice, interleaved f4s), ln = lane>>4 -> 4 n-rows.
// 1 B LDS per FMA; conflict-free contiguous b128 reads.
__global__ __launch_bounds__(256) void k_mlp(const float* __restrict__ W1,
                                             float* __restrict__ ws) {
  __shared__ float lds[16704];
  const int bx = blockIdx.x;
  const int bt = bx & 3, nt = (bx >> 2) & 15, ks = bx >> 6;
  const int t = threadIdx.x, w = t >> 6, lane = t & 63;
  const int lk = lane & 15, ln = lane >> 4;
  const int n0 = nt * 64 + w * 16 + ln * 4;  // this lane's 4 W1 rows
  const int kb0 = ks * 768;
  const float* feat = ws + WS_FEAT;
  float acc[16][4];
#pragma unroll
  for (int b = 0; b < 16; ++b)
#pragma unroll
    for (int r = 0; r < 4; ++r) acc[b][r] = 0.f;

  for (int step = 0; step < 3; ++step) {
    const int kb = kb0 + step * 256;
    __syncthreads();
#pragma unroll
    for (int j = 0; j < 4; ++j) {
      const int idx = t + 256 * j;            // f4 id, 16 rows x 64
      const int row = idx >> 6, c4 = idx & 63;
      *(float4*)&lds[row * 256 + 4 * c4] =
          *(const float4*)&feat[(size_t)(bt * 16 + row) * DH + kb + 4 * c4];
    }
    __syncthreads();
    // W frags: k-cols {4lk..4lk+3} + i*64, rows n0..n0+3
    float4 wf[4][4];
#pragma unroll
    for (int r = 0; r < 4; ++r)
#pragma unroll
      for (int i = 0; i < 4; ++i)
        wf[r][i] = *(const float4*)&W1[(size_t)(n0 + r) * DH + kb + i * 64 + 4 * lk];
#pragma unroll
    for (int b = 0; b < 16; ++b) {
      const float* lb = &lds[b * 256 + 4 * lk];
      const float4 f0 = *(const float4*)(lb);
      const float4 f1 = *(const float4*)(lb + 64);
      const float4 f2 = *(const float4*)(lb + 128);
      const float4 f3 = *(const float4*)(lb + 192);
#pragma unroll
      for (int r = 0; r < 4; ++r)
        acc[b][r] += dot4(f0, wf[r][0]) + dot4(f1, wf[r][1]) +
                     dot4(f2, wf[r][2]) + dot4(f3, wf[r][3]);
    }
  }
  // reduce over 16 lk lanes via LDS transpose (stride 260 to spread banks)
  __syncthreads();
  float* R = &lds[w * 4176];
#pragma unroll
  for (int b = 0; b < 16; ++b)
    *(float4*)&R[lk * 260 + b * 16 + ln * 4] =
        make_float4(acc[b][0], acc[b][1], acc[b][2], acc[b][3]);
  __syncthreads();
  float4 h = make_float4(0.f, 0.f, 0.f, 0.f);
#pragma unroll
  for (int k2 = 0; k2 < 16; ++k2) {
    const float4 v = *(const float4*)&R[k2 * 260 + lane * 4];
    h.x += v.x; h.y += v.y; h.z += v.z; h.w += v.w;
  }
  // lane owns outputs (b', n'0..n'0+3): id = lane*4 -> b' = lane>>2, n'0 = (lane*4)&15
  const int bo = bt * 16 + (lane >> 2);
  const int no = nt * 64 + w * 16 + ((lane * 4) & 15);
  *(float4*)&ws[WS_HPART + ((size_t)ks * 64 + bo) * 1024 + no] = h;
}

// ------------------------------------------------------------------- out ----
__global__ __launch_bounds__(256) void k_out(const float* __restrict__ b1,
                                             const float* __restrict__ alpha,
                                             const float* __restrict__ W2,
                                             const float* __restrict__ b2,
                                             const float* __restrict__ ws,
                                             float* __restrict__ out) {
  const int b = blockIdx.x;
  const int t = threadIdx.x;
  const float al = alpha[0];
  float partial = 0.f;
#pragma unroll
  for (int u = 0; u < 4; ++u) {
    const int n = t + 256 * u;
    float hs = 0.f;
#pragma unroll
    for (int ksp = 0; ksp < 8; ++ksp)
      hs += ws[WS_HPART + ((size_t)ksp * 64 + b) * 1024 + n];
    float h = hs + b1[n];
    h = (h >= 0.f) ? h : al * h;
    partial += h * W2[n];
  }
#pragma unroll
  for (int o = 1; o < 64; o <<= 1) partial += __shfl_xor(partial, o, 64);
  __shared__ float wsum[4];
  if ((t & 63) == 0) wsum[t >> 6] = partial;
  __syncthreads();
  if (t == 0) out[b] = b2[0] + wsum[0] + wsum[1] + wsum[2] + wsum[3];
}

// ------------------------------------------------------------------ launch --
extern "C" void kernel_launch(void* const* d_in, const int* in_sizes, int n_in,
                              void* d_out, int out_size, void* d_ws, size_t ws_size,
                              hipStream_t stream) {
  const float* x     = (const float*)d_in[0];
  const float* Wm    = (const float*)d_in[1];
  const float* W1    = (const float*)d_in[2];
  const float* b1    = (const float*)d_in[3];
  const float* alpha = (const float*)d_in[4];
  const float* W2    = (const float*)d_in[5];
  const float* b2    = (const float*)d_in[6];
  const int* locs    = (const int*)d_in[7];
  const int* seps    = (const int*)d_in[8];
  float* out = (float*)d_out;
  float* ws = (float*)d_ws;

  hipLaunchKernelGGL(k_entity, dim3(6, 64), dim3(256), 0, stream, x, locs, ws);
  hipLaunchKernelGGL(k_qgemv, dim3(384), dim3(256), 0, stream, Wm, ws);
  hipLaunchKernelGGL(k_flash, dim3(NB * 32), dim3(64), 0, stream, x, locs, seps, ws);
  hipLaunchKernelGGL(k_comb, dim3(NB * 2), dim3(256), 0, stream, ws);
  hipLaunchKernelGGL(k_mlp, dim3(512), dim3(256), 0, stream, W1, ws);
  hipLaunchKernelGGL(k_out, dim3(NB), dim3(256), 0, stream, b1, alpha, W2, b2, ws, out);
}